// Round 8
// baseline (521.794 us; speedup 1.0000x reference)
//
#include <hip/hip_runtime.h>
#include <hip/hip_bf16.h>

// AttentionDownsample: B=256, N=196(14x14), NQ=49(7x7 stride2), IN=384,
// HEADS=12, KEY=16, VAL=32, KV=576, OUT=512.
// I/O contract (R8, from stub header + R3/R7 evidence): inputs fp32,
// bias_idxs int32, OUTPUT fp32. Internal: bf16 MFMA, fp32 accum.

typedef __bf16 bf16;
typedef float f32x4 __attribute__((ext_vector_type(4)));
typedef __bf16 bf16x8 __attribute__((ext_vector_type(8)));

// ---------------------------------------------------------------------------
// BN scale/shift precompute: sc = g*rsqrt(v+eps), sh = b - m*sc
__global__ void prep_kernel(const float* kv_g, const float* kv_b, const float* kv_m, const float* kv_v,
                            const float* q_g,  const float* q_b,  const float* q_m,  const float* q_v,
                            const float* p_g,  const float* p_b,  const float* p_m,  const float* p_v,
                            float* scbuf) {
  int i = blockIdx.x * 256 + threadIdx.x;
  const float *g, *bb, *mm, *vv;
  float *sc, *sh;
  int c;
  if (i < 576)        { c = i;       g = kv_g; bb = kv_b; mm = kv_m; vv = kv_v; sc = scbuf;        sh = scbuf + 576;  }
  else if (i < 768)   { c = i - 576; g = q_g;  bb = q_b;  mm = q_m;  vv = q_v;  sc = scbuf + 1152; sh = scbuf + 1344; }
  else if (i < 1280)  { c = i - 768; g = p_g;  bb = p_b;  mm = p_m;  vv = p_v;  sc = scbuf + 1536; sh = scbuf + 2048; }
  else return;
  float sv = g[c] * rsqrtf(vv[c] + 1e-5f);
  sc[c] = sv;
  sh[c] = bb[c] - mm[c] * sv;
}

// ---------------------------------------------------------------------------
// attn_bias gather: biasp[(h*49+q)*196 + j] = biases[h, bias_idxs[q,j]]
__global__ void bias_kernel(const float* biases, const int* idxs, float* biasp) {
  int i = blockIdx.x * 256 + threadIdx.x;
  if (i < 12 * 49 * 196) {
    int h = i / (49 * 196);
    int rem = i - h * (49 * 196);
    biasp[i] = biases[h * 196 + idxs[rem]];
  }
}

// ---------------------------------------------------------------------------
// GEMM C[M,N] = A[mbase+m, 384] @ W[N,384]^T, BN epilogue.
// Tile 128x64, 128 threads (2 waves), wave does 64x64 via 4x4 mfma 16x16x32.
// A_BF16: A is internal bf16 buffer; else fp32. W always external fp32.
// OutT: bf16 (internal) or float (d_out).
// GATHER: A-row m -> x row b*196 + (qq/7)*28 + (qq%7)*2 (strided 2x2 sample).
template<bool GATHER, bool A_BF16, typename OutT>
__global__ __launch_bounds__(128)
void gemm_bn_kernel(const void* __restrict__ A, const float* __restrict__ W,
                    const float* __restrict__ sc, const float* __restrict__ sh,
                    OutT* __restrict__ C, int N, long mbase) {
  __shared__ __attribute__((aligned(16))) bf16 As[128 * 32];
  __shared__ __attribute__((aligned(16))) bf16 Ws[64 * 32];
  const int tid  = threadIdx.x;
  const int lane = tid & 63;
  const int wid  = tid >> 6;
  const int m0 = blockIdx.y * 128;
  const int n0 = blockIdx.x * 64;
  const int c8  = tid & 3;        // which 8-col chunk of the 32-wide k-slab
  const int rbs = tid >> 2;       // row within a 32-row group

  long eA[4]; int lAoff[4];
#pragma unroll
  for (int rr = 0; rr < 4; ++rr) {
    int r = rr * 32 + rbs;
    long arow;
    if (GATHER) {
      int m = m0 + r;
      int b = m / 49;
      int qq = m - b * 49;
      arow = (long)b * 196 + (qq / 7) * 28 + (qq % 7) * 2;
    } else {
      arow = mbase + m0 + r;
    }
    eA[rr] = arow * 384 + c8 * 8;
    lAoff[rr] = r * 32 + c8 * 8;
  }
  long eW[2]; int lWoff[2];
#pragma unroll
  for (int rr = 0; rr < 2; ++rr) {
    int r = rr * 32 + rbs;
    eW[rr] = (long)(n0 + r) * 384 + c8 * 8;
    lWoff[rr] = r * 32 + c8 * 8;
  }

  f32x4 acc[4][4] = {};
  const int mrow = lane & 15;
  const int quad = lane >> 4;

  for (int k0 = 0; k0 < 384; k0 += 32) {
    bf16x8 ta[4], tw[2];
    if (A_BF16) {
#pragma unroll
      for (int rr = 0; rr < 4; ++rr) ta[rr] = *(const bf16x8*)((const bf16*)A + eA[rr] + k0);
    } else {
#pragma unroll
      for (int rr = 0; rr < 4; ++rr) {
        const float* p = (const float*)A + eA[rr] + k0;
        f32x4 lo = *(const f32x4*)p, hi = *(const f32x4*)(p + 4);
        bf16x8 t;
        t[0]=(bf16)lo[0]; t[1]=(bf16)lo[1]; t[2]=(bf16)lo[2]; t[3]=(bf16)lo[3];
        t[4]=(bf16)hi[0]; t[5]=(bf16)hi[1]; t[6]=(bf16)hi[2]; t[7]=(bf16)hi[3];
        ta[rr] = t;
      }
    }
#pragma unroll
    for (int rr = 0; rr < 2; ++rr) {
      const float* p = W + eW[rr] + k0;
      f32x4 lo = *(const f32x4*)p, hi = *(const f32x4*)(p + 4);
      bf16x8 t;
      t[0]=(bf16)lo[0]; t[1]=(bf16)lo[1]; t[2]=(bf16)lo[2]; t[3]=(bf16)lo[3];
      t[4]=(bf16)hi[0]; t[5]=(bf16)hi[1]; t[6]=(bf16)hi[2]; t[7]=(bf16)hi[3];
      tw[rr] = t;
    }
    __syncthreads();  // previous iter's LDS reads complete before overwrite
#pragma unroll
    for (int rr = 0; rr < 4; ++rr) *(bf16x8*)(As + lAoff[rr]) = ta[rr];
#pragma unroll
    for (int rr = 0; rr < 2; ++rr) *(bf16x8*)(Ws + lWoff[rr]) = tw[rr];
    __syncthreads();

    bf16x8 af[4], bw[4];
#pragma unroll
    for (int mi = 0; mi < 4; ++mi)
      af[mi] = *(const bf16x8*)(As + (wid * 64 + mi * 16 + mrow) * 32 + quad * 8);
#pragma unroll
    for (int ni = 0; ni < 4; ++ni)
      bw[ni] = *(const bf16x8*)(Ws + (ni * 16 + mrow) * 32 + quad * 8);
#pragma unroll
    for (int mi = 0; mi < 4; ++mi)
#pragma unroll
      for (int ni = 0; ni < 4; ++ni)
        acc[mi][ni] = __builtin_amdgcn_mfma_f32_16x16x32_bf16(af[mi], bw[ni], acc[mi][ni], 0, 0, 0);
  }

  // epilogue: C/D layout col=lane&15, row=quad*4+reg (m89-verified)
#pragma unroll
  for (int ni = 0; ni < 4; ++ni) {
    int col = n0 + ni * 16 + mrow;
    float s = sc[col], t = sh[col];
#pragma unroll
    for (int mi = 0; mi < 4; ++mi) {
#pragma unroll
      for (int reg = 0; reg < 4; ++reg) {
        int row = m0 + wid * 64 + mi * 16 + quad * 4 + reg;
        C[(long)row * N + col] = (OutT)(acc[mi][ni][reg] * s + t);
      }
    }
  }
}

// ---------------------------------------------------------------------------
// Fused MFMA attention per (b,h): S = q@k^T*0.25 + bias -> softmax -> @v
// -> SiLU. 4 waves; wave w owns q-rows [16w,16w+16). K=16 zero-padded to 32.
// Exonerated by R4==R5 bit-identical outputs. kvbuf holds chunk [b0,b0+64).
__global__ __launch_bounds__(256)
void attn_kernel(const bf16* __restrict__ kvbuf, const bf16* __restrict__ qbuf,
                 const float* __restrict__ biasp, bf16* __restrict__ aout,
                 int b0) {
  __shared__ __attribute__((aligned(16))) bf16 q_s[64 * 32];     // rows>=49, d>=16 zero
  __shared__ __attribute__((aligned(16))) bf16 k_s[208 * 32];    // rows>=196, d>=16 zero
  __shared__ __attribute__((aligned(16))) bf16 vT_s[32 * 224];   // [d][j], j>=196 zero
  __shared__ __attribute__((aligned(16))) bf16 P_s[4 * 16 * 224];// per-wave P tile
  const int bh = blockIdx.x;
  const int bl = bh / 12;            // local batch within chunk
  const int h = bh - bl * 12;
  const int bg = b0 + bl;            // global batch
  const int tid  = threadIdx.x;
  const int lane = tid & 63;
  const int wid  = tid >> 6;
  const long kv_base = ((long)bl * 196) * 576 + h * 48;

  for (int i = tid; i < 64 * 32; i += 256) {
    int r = i >> 5, d = i & 31;
    q_s[i] = (r < 49 && d < 16) ? qbuf[((long)bg * 49 + r) * 192 + h * 16 + d] : (bf16)0.0f;
  }
  for (int i = tid; i < 208 * 32; i += 256) {
    int r = i >> 5, d = i & 31;
    k_s[i] = (r < 196 && d < 16) ? kvbuf[kv_base + (long)r * 576 + d] : (bf16)0.0f;
  }
  for (int i = tid; i < 32 * 224; i += 256) {
    int d = i / 224, j = i - d * 224;
    vT_s[i] = (j < 196) ? kvbuf[kv_base + (long)j * 576 + 16 + d] : (bf16)0.0f;
  }
  __syncthreads();

  const int mrow = lane & 15;
  const int quad = lane >> 4;

  // QK^T: 13 n-tiles of 16 keys
  f32x4 s[13];
  bf16x8 aq = *(const bf16x8*)(q_s + (wid * 16 + mrow) * 32 + quad * 8);
#pragma unroll
  for (int jt = 0; jt < 13; ++jt) {
    bf16x8 bk = *(const bf16x8*)(k_s + (jt * 16 + mrow) * 32 + quad * 8);
    f32x4 z = {};
    s[jt] = __builtin_amdgcn_mfma_f32_16x16x32_bf16(aq, bk, z, 0, 0, 0);
  }

  const int rbase = wid * 16 + quad * 4;
#pragma unroll
  for (int jt = 0; jt < 13; ++jt) {
    int c = jt * 16 + mrow;
#pragma unroll
    for (int reg = 0; reg < 4; ++reg) {
      int r = rbase + reg;
      float v = s[jt][reg] * 0.25f;
      if (c < 196) {
        if (r < 49) v += biasp[((long)h * 49 + r) * 196 + c];
      } else {
        v = -1e30f;
      }
      s[jt][reg] = v;
    }
  }
  // softmax over 196 cols: row lives on the 16 lanes sharing `quad`
  float mx[4], sm[4];
#pragma unroll
  for (int reg = 0; reg < 4; ++reg) {
    float m = -1e30f;
#pragma unroll
    for (int jt = 0; jt < 13; ++jt) m = fmaxf(m, s[jt][reg]);
    m = fmaxf(m, __shfl_xor(m, 1));
    m = fmaxf(m, __shfl_xor(m, 2));
    m = fmaxf(m, __shfl_xor(m, 4));
    m = fmaxf(m, __shfl_xor(m, 8));
    mx[reg] = m;
  }
#pragma unroll
  for (int jt = 0; jt < 13; ++jt) {
    int c = jt * 16 + mrow;
#pragma unroll
    for (int reg = 0; reg < 4; ++reg)
      s[jt][reg] = (c < 196) ? __expf(s[jt][reg] - mx[reg]) : 0.0f;
  }
#pragma unroll
  for (int reg = 0; reg < 4; ++reg) {
    float t = 0.0f;
#pragma unroll
    for (int jt = 0; jt < 13; ++jt) t += s[jt][reg];
    t += __shfl_xor(t, 1);
    t += __shfl_xor(t, 2);
    t += __shfl_xor(t, 4);
    t += __shfl_xor(t, 8);
    sm[reg] = 1.0f / t;
  }
  // P: C-layout -> A-layout via LDS round-trip (bf16)
  bf16* Pw = P_s + wid * 16 * 224;
#pragma unroll
  for (int jt = 0; jt < 13; ++jt) {
#pragma unroll
    for (int reg = 0; reg < 4; ++reg)
      Pw[(quad * 4 + reg) * 224 + jt * 16 + mrow] = (bf16)(s[jt][reg] * sm[reg]);
  }
#pragma unroll
  for (int reg = 0; reg < 4; ++reg)
    Pw[(quad * 4 + reg) * 224 + 208 + mrow] = (bf16)0.0f; // zero k-pad 208..223
  __syncthreads();

  // PV: out[16x32], K=224 in 7 steps of 32
  f32x4 o[2] = {};
#pragma unroll
  for (int kk = 0; kk < 7; ++kk) {
    bf16x8 ap = *(const bf16x8*)(Pw + mrow * 224 + kk * 32 + quad * 8);
#pragma unroll
    for (int nt = 0; nt < 2; ++nt) {
      bf16x8 bv = *(const bf16x8*)(vT_s + (nt * 16 + mrow) * 224 + kk * 32 + quad * 8);
      o[nt] = __builtin_amdgcn_mfma_f32_16x16x32_bf16(ap, bv, o[nt], 0, 0, 0);
    }
  }
  // SiLU + store to (B,49,384): channel = h*32 + d
#pragma unroll
  for (int nt = 0; nt < 2; ++nt) {
#pragma unroll
    for (int reg = 0; reg < 4; ++reg) {
      int r = rbase + reg;
      if (r < 49) {
        float x = o[nt][reg];
        float sil = x / (1.0f + __expf(-x));
        aout[((long)bg * 49 + r) * 384 + h * 32 + nt * 16 + mrow] = (bf16)sil;
      }
    }
  }
}

// ---------------------------------------------------------------------------
extern "C" void kernel_launch(void* const* d_in, const int* in_sizes, int n_in,
                              void* d_out, int out_size, void* d_ws, size_t ws_size,
                              hipStream_t stream) {
  const float* x      = (const float*)d_in[0];
  const float* kv_w   = (const float*)d_in[1];
  const float* q_w    = (const float*)d_in[6];
  const float* pj_w   = (const float*)d_in[11];
  const float* biases = (const float*)d_in[16];
  const int*   bidx   = (const int*)d_in[17];

  char* ws = (char*)d_ws;
  float* scbuf = (float*)ws;                  // 2560 f32 = 10,240 B
  float* biasp = (float*)(ws + 10256);        // (12,49,196) f32 = 460,992 B
  bf16*  qbuf  = (bf16*)(ws + 471296);        // (12544,192) bf16
  bf16*  aout  = (bf16*)(ws + 5288192);       // (12544,384) bf16
  bf16*  kvbuf = (bf16*)(ws + 14921984);      // chunk (64*196,576) bf16
                                              // end ~29.4 MB

  prep_kernel<<<5, 256, 0, stream>>>(
      (const float*)d_in[2],  (const float*)d_in[3],  (const float*)d_in[4],  (const float*)d_in[5],
      (const float*)d_in[7],  (const float*)d_in[8],  (const float*)d_in[9],  (const float*)d_in[10],
      (const float*)d_in[12], (const float*)d_in[13], (const float*)d_in[14], (const float*)d_in[15],
      scbuf);
  bias_kernel<<<451, 256, 0, stream>>>(biases, bidx, biasp);
  // q = BN(xq @ q_w^T): M=12544 (gathered rows), N=192
  gemm_bn_kernel<true, false, bf16><<<dim3(3, 98), 128, 0, stream>>>(
      x, q_w, scbuf + 1152, scbuf + 1344, qbuf, 192, 0);
  // kv + attention in 4 chunks of 64 batches (kvbuf reused per chunk)
  for (int ch = 0; ch < 4; ++ch) {
    gemm_bn_kernel<false, false, bf16><<<dim3(9, 98), 128, 0, stream>>>(
        x, kv_w, scbuf, scbuf + 576, kvbuf, 576, (long)ch * 12544);
    attn_kernel<<<768, 256, 0, stream>>>(kvbuf, qbuf, biasp, aout, ch * 64);
  }
  // out = BN(silu_attn @ pj_w^T): M=12544, N=512 — OUTPUT IS FP32
  gemm_bn_kernel<false, true, float><<<dim3(8, 98), 128, 0, stream>>>(
      aout, pj_w, scbuf + 1536, scbuf + 2048, (float*)d_out, 512, 0);
}

// Round 9
// 365.764 us; speedup vs baseline: 1.4266x; 1.4266x over previous
//
#include <hip/hip_runtime.h>
#include <hip/hip_bf16.h>

// AttentionDownsample: B=256, N=196(14x14), NQ=49(7x7 stride2), IN=384,
// HEADS=12, KEY=16, VAL=32, KV=576, OUT=512.
// Contract (verified R8): inputs fp32, bias_idxs int32, output fp32.
// Internal: bf16 MFMA, fp32 accum.
// R9: de-chunked; kv/q GEMM epilogues scatter to per-(b,h) attention-ready
// layouts (k [196x16], vT [32x196], q [49x16] contiguous); attention staging
// vectorized; LDS 59->42KB via P-overlay.

typedef __bf16 bf16;
typedef float f32x4 __attribute__((ext_vector_type(4)));
typedef __bf16 bf16x8 __attribute__((ext_vector_type(8)));
typedef __bf16 bf16x4 __attribute__((ext_vector_type(4)));

// per-(b,h) kv2 block: k [196][16] el at +0, vT [32][196] el at +6272 B; 18816 B total
#define KV2_BLK 18816
#define KV2_VOFF 6272
#define Q2_BLK 1568

// ---------------------------------------------------------------------------
__global__ void prep_kernel(const float* kv_g, const float* kv_b, const float* kv_m, const float* kv_v,
                            const float* q_g,  const float* q_b,  const float* q_m,  const float* q_v,
                            const float* p_g,  const float* p_b,  const float* p_m,  const float* p_v,
                            float* scbuf) {
  int i = blockIdx.x * 256 + threadIdx.x;
  const float *g, *bb, *mm, *vv;
  float *sc, *sh;
  int c;
  if (i < 576)        { c = i;       g = kv_g; bb = kv_b; mm = kv_m; vv = kv_v; sc = scbuf;        sh = scbuf + 576;  }
  else if (i < 768)   { c = i - 576; g = q_g;  bb = q_b;  mm = q_m;  vv = q_v;  sc = scbuf + 1152; sh = scbuf + 1344; }
  else if (i < 1280)  { c = i - 768; g = p_g;  bb = p_b;  mm = p_m;  vv = p_v;  sc = scbuf + 1536; sh = scbuf + 2048; }
  else return;
  float sv = g[c] * rsqrtf(vv[c] + 1e-5f);
  sc[c] = sv;
  sh[c] = bb[c] - mm[c] * sv;
}

// ---------------------------------------------------------------------------
__global__ void bias_kernel(const float* biases, const int* idxs, float* biasp) {
  int i = blockIdx.x * 256 + threadIdx.x;
  if (i < 12 * 49 * 196) {
    int h = i / (49 * 196);
    int rem = i - h * (49 * 196);
    biasp[i] = biases[h * 196 + idxs[rem]];
  }
}

// ---------------------------------------------------------------------------
// GEMM C = A[M,384] @ W[N,384]^T, BN epilogue.
// Tile 128x64, 128 threads (2 waves), wave does 64x64 via 4x4 mfma 16x16x32.
// EPI: 0 = plain fp32 C[m*N+col] (pj) | 1 = kv scatter | 2 = q scatter.
// A_BF16: A internal bf16 (pj); else fp32 external.
// GATHER: A-row m -> x row b*196 + (qq/7)*28 + (qq%7)*2.
template<int EPI, bool GATHER, bool A_BF16>
__global__ __launch_bounds__(128)
void gemm_bn_kernel(const void* __restrict__ A, const float* __restrict__ W,
                    const float* __restrict__ sc, const float* __restrict__ sh,
                    char* __restrict__ out, int N) {
  __shared__ __attribute__((aligned(16))) bf16 As[128 * 32];
  __shared__ __attribute__((aligned(16))) bf16 Ws[64 * 32];
  const int tid  = threadIdx.x;
  const int lane = tid & 63;
  const int wid  = tid >> 6;
  const int m0 = blockIdx.y * 128;
  const int n0 = blockIdx.x * 64;
  const int c8  = tid & 3;
  const int rbs = tid >> 2;

  long eA[4]; int lAoff[4];
#pragma unroll
  for (int rr = 0; rr < 4; ++rr) {
    int r = rr * 32 + rbs;
    long arow;
    if (GATHER) {
      int m = m0 + r;
      int b = m / 49;
      int qq = m - b * 49;
      arow = (long)b * 196 + (qq / 7) * 28 + (qq % 7) * 2;
    } else {
      arow = m0 + r;
    }
    eA[rr] = arow * 384 + c8 * 8;
    lAoff[rr] = r * 32 + c8 * 8;
  }
  long eW[2]; int lWoff[2];
#pragma unroll
  for (int rr = 0; rr < 2; ++rr) {
    int r = rr * 32 + rbs;
    eW[rr] = (long)(n0 + r) * 384 + c8 * 8;
    lWoff[rr] = r * 32 + c8 * 8;
  }

  f32x4 acc[4][4] = {};
  const int mrow = lane & 15;
  const int quad = lane >> 4;

  for (int k0 = 0; k0 < 384; k0 += 32) {
    bf16x8 ta[4], tw[2];
    if (A_BF16) {
#pragma unroll
      for (int rr = 0; rr < 4; ++rr) ta[rr] = *(const bf16x8*)((const bf16*)A + eA[rr] + k0);
    } else {
#pragma unroll
      for (int rr = 0; rr < 4; ++rr) {
        const float* p = (const float*)A + eA[rr] + k0;
        f32x4 lo = *(const f32x4*)p, hi = *(const f32x4*)(p + 4);
        bf16x8 t;
        t[0]=(bf16)lo[0]; t[1]=(bf16)lo[1]; t[2]=(bf16)lo[2]; t[3]=(bf16)lo[3];
        t[4]=(bf16)hi[0]; t[5]=(bf16)hi[1]; t[6]=(bf16)hi[2]; t[7]=(bf16)hi[3];
        ta[rr] = t;
      }
    }
#pragma unroll
    for (int rr = 0; rr < 2; ++rr) {
      const float* p = W + eW[rr] + k0;
      f32x4 lo = *(const f32x4*)p, hi = *(const f32x4*)(p + 4);
      bf16x8 t;
      t[0]=(bf16)lo[0]; t[1]=(bf16)lo[1]; t[2]=(bf16)lo[2]; t[3]=(bf16)lo[3];
      t[4]=(bf16)hi[0]; t[5]=(bf16)hi[1]; t[6]=(bf16)hi[2]; t[7]=(bf16)hi[3];
      tw[rr] = t;
    }
    __syncthreads();
#pragma unroll
    for (int rr = 0; rr < 4; ++rr) *(bf16x8*)(As + lAoff[rr]) = ta[rr];
#pragma unroll
    for (int rr = 0; rr < 2; ++rr) *(bf16x8*)(Ws + lWoff[rr]) = tw[rr];
    __syncthreads();

    bf16x8 af[4], bw[4];
#pragma unroll
    for (int mi = 0; mi < 4; ++mi)
      af[mi] = *(const bf16x8*)(As + (wid * 64 + mi * 16 + mrow) * 32 + quad * 8);
#pragma unroll
    for (int ni = 0; ni < 4; ++ni)
      bw[ni] = *(const bf16x8*)(Ws + (ni * 16 + mrow) * 32 + quad * 8);
#pragma unroll
    for (int mi = 0; mi < 4; ++mi)
#pragma unroll
      for (int ni = 0; ni < 4; ++ni)
        acc[mi][ni] = __builtin_amdgcn_mfma_f32_16x16x32_bf16(af[mi], bw[ni], acc[mi][ni], 0, 0, 0);
  }

  // epilogue: C/D layout col=lane&15, row=quad*4+reg
#pragma unroll
  for (int ni = 0; ni < 4; ++ni) {
    int col = n0 + ni * 16 + mrow;
    float s = sc[col], t = sh[col];
    int h = 0, dd = 0;
    if (EPI == 1) { h = col / 48; dd = col - h * 48; }
    if (EPI == 2) { h = col >> 4; dd = col & 15; }
#pragma unroll
    for (int mi = 0; mi < 4; ++mi) {
#pragma unroll
      for (int reg = 0; reg < 4; ++reg) {
        int m = m0 + wid * 64 + mi * 16 + quad * 4 + reg;
        float y = acc[mi][ni][reg] * s + t;
        if (EPI == 0) {
          ((float*)out)[(long)m * N + col] = y;
        } else if (EPI == 1) {
          int b = m / 196, j = m - b * 196;
          char* base = out + ((long)(b * 12 + h)) * KV2_BLK;
          if (dd < 16) ((bf16*)base)[j * 16 + dd] = (bf16)y;
          else ((bf16*)(base + KV2_VOFF))[(dd - 16) * 196 + j] = (bf16)y;
        } else {
          int b = m / 49, qq = m - b * 49;
          ((bf16*)(out + ((long)(b * 12 + h)) * Q2_BLK))[qq * 16 + dd] = (bf16)y;
        }
      }
    }
  }
}

// ---------------------------------------------------------------------------
// Fused MFMA attention, one block per (b,h). 256 threads (4 waves), wave w
// owns q-rows [16w,16w+16). K=16 zero-padded to 32 for QK MFMA.
// LDS (42 KB): [vT 14336][q 4096][k 13312]; P (28672) overlays q+k after QK.
__global__ __launch_bounds__(256)
void attn_kernel(const char* __restrict__ kv2, const char* __restrict__ qb2,
                 const float* __restrict__ biasp, bf16* __restrict__ aout) {
  __shared__ __attribute__((aligned(16))) char smem[43008];
  bf16* vT_s = (bf16*)smem;            // [32][224]
  bf16* q_s  = (bf16*)(smem + 14336);  // [64][32]
  bf16* k_s  = (bf16*)(smem + 18432);  // [208][32]
  bf16* P_s  = (bf16*)(smem + 14336);  // [64][224] overlay (post-QK)

  const int bh = blockIdx.x;
  const int b = bh / 12;
  const int h = bh - b * 12;
  const int tid  = threadIdx.x;
  const int lane = tid & 63;
  const int wid  = tid >> 6;

  const bf16* ksrc = (const bf16*)(kv2 + (long)bh * KV2_BLK);
  const bf16* vsrc = (const bf16*)(kv2 + (long)bh * KV2_BLK + KV2_VOFF);
  const bf16* qsrc = (const bf16*)(qb2 + (long)bh * Q2_BLK);

  {
    // q: [49][16] -> q_s [64][32], zero-pad
    int row = tid >> 2, cg = tid & 3;
    bf16x8 z = {};
    *(bf16x8*)(q_s + row * 32 + cg * 8) =
        (row < 49 && cg < 2) ? *(const bf16x8*)(qsrc + row * 16 + cg * 8) : z;
    // k: [196][16] -> k_s [208][32], zero-pad
    for (int i = tid; i < 832; i += 256) {
      int r = i >> 2, c = i & 3;
      *(bf16x8*)(k_s + r * 32 + c * 8) =
          (r < 196 && c < 2) ? *(const bf16x8*)(ksrc + r * 16 + c * 8) : z;
    }
    // vT: [32][196] -> vT_s [32][224], zero-pad (4-el units: 196 = 49*4)
    bf16x4 z4 = {};
    for (int i = tid; i < 1792; i += 256) {
      int r = i / 56, c = i - r * 56;
      *(bf16x4*)(vT_s + r * 224 + c * 4) =
          (c < 49) ? *(const bf16x4*)(vsrc + r * 196 + c * 4) : z4;
    }
  }
  __syncthreads();

  const int mrow = lane & 15;
  const int quad = lane >> 4;

  // QK^T: 13 n-tiles of 16 keys
  f32x4 s[13];
  bf16x8 aq = *(const bf16x8*)(q_s + (wid * 16 + mrow) * 32 + quad * 8);
#pragma unroll
  for (int jt = 0; jt < 13; ++jt) {
    bf16x8 bk = *(const bf16x8*)(k_s + (jt * 16 + mrow) * 32 + quad * 8);
    f32x4 z = {};
    s[jt] = __builtin_amdgcn_mfma_f32_16x16x32_bf16(aq, bk, z, 0, 0, 0);
  }

  const int rbase = wid * 16 + quad * 4;
#pragma unroll
  for (int jt = 0; jt < 13; ++jt) {
    int c = jt * 16 + mrow;
#pragma unroll
    for (int reg = 0; reg < 4; ++reg) {
      int r = rbase + reg;
      float v = s[jt][reg] * 0.25f;
      if (c < 196) {
        if (r < 49) v += biasp[((long)h * 49 + r) * 196 + c];
      } else {
        v = -1e30f;
      }
      s[jt][reg] = v;
    }
  }
  // softmax over 196 cols (row spread over 16 lanes sharing quad)
  float mx[4], sm[4];
#pragma unroll
  for (int reg = 0; reg < 4; ++reg) {
    float m = -1e30f;
#pragma unroll
    for (int jt = 0; jt < 13; ++jt) m = fmaxf(m, s[jt][reg]);
    m = fmaxf(m, __shfl_xor(m, 1));
    m = fmaxf(m, __shfl_xor(m, 2));
    m = fmaxf(m, __shfl_xor(m, 4));
    m = fmaxf(m, __shfl_xor(m, 8));
    mx[reg] = m;
  }
#pragma unroll
  for (int jt = 0; jt < 13; ++jt) {
    int c = jt * 16 + mrow;
#pragma unroll
    for (int reg = 0; reg < 4; ++reg)
      s[jt][reg] = (c < 196) ? __expf(s[jt][reg] - mx[reg]) : 0.0f;
  }
#pragma unroll
  for (int reg = 0; reg < 4; ++reg) {
    float t = 0.0f;
#pragma unroll
    for (int jt = 0; jt < 13; ++jt) t += s[jt][reg];
    t += __shfl_xor(t, 1);
    t += __shfl_xor(t, 2);
    t += __shfl_xor(t, 4);
    t += __shfl_xor(t, 8);
    sm[reg] = 1.0f / t;
  }

  __syncthreads();  // all waves done reading q_s/k_s before P overlay writes

  // P: C-layout -> A-layout via LDS round-trip (own-wave region)
  bf16* Pw = P_s + wid * 16 * 224;
#pragma unroll
  for (int jt = 0; jt < 13; ++jt) {
#pragma unroll
    for (int reg = 0; reg < 4; ++reg)
      Pw[(quad * 4 + reg) * 224 + jt * 16 + mrow] = (bf16)(s[jt][reg] * sm[reg]);
  }
#pragma unroll
  for (int reg = 0; reg < 4; ++reg)
    Pw[(quad * 4 + reg) * 224 + 208 + mrow] = (bf16)0.0f; // zero k-pad

  // PV: out[16x32], K=224 in 7 steps of 32 (same-wave P read; vT_s stable)
  f32x4 o[2] = {};
#pragma unroll
  for (int kk = 0; kk < 7; ++kk) {
    bf16x8 ap = *(const bf16x8*)(Pw + mrow * 224 + kk * 32 + quad * 8);
#pragma unroll
    for (int nt = 0; nt < 2; ++nt) {
      bf16x8 bv = *(const bf16x8*)(vT_s + (nt * 16 + mrow) * 224 + kk * 32 + quad * 8);
      o[nt] = __builtin_amdgcn_mfma_f32_16x16x32_bf16(ap, bv, o[nt], 0, 0, 0);
    }
  }
  // SiLU + store to aout (B,49,384): channel = h*32 + d
#pragma unroll
  for (int nt = 0; nt < 2; ++nt) {
#pragma unroll
    for (int reg = 0; reg < 4; ++reg) {
      int r = rbase + reg;
      if (r < 49) {
        float x = o[nt][reg];
        float sil = x / (1.0f + __expf(-x));
        aout[((long)b * 49 + r) * 384 + h * 32 + nt * 16 + mrow] = (bf16)sil;
      }
    }
  }
}

// ---------------------------------------------------------------------------
extern "C" void kernel_launch(void* const* d_in, const int* in_sizes, int n_in,
                              void* d_out, int out_size, void* d_ws, size_t ws_size,
                              hipStream_t stream) {
  const float* x      = (const float*)d_in[0];
  const float* kv_w   = (const float*)d_in[1];
  const float* q_w    = (const float*)d_in[6];
  const float* pj_w   = (const float*)d_in[11];
  const float* biases = (const float*)d_in[16];
  const int*   bidx   = (const int*)d_in[17];

  char* ws = (char*)d_ws;
  float* scbuf = (float*)ws;                  // 2560 f32
  float* biasp = (float*)(ws + 10256);        // (12,49,196) f32
  char*  qb2   = ws + 471296;                 // 3072 x 1568 B
  bf16*  aout  = (bf16*)(ws + 5288192);       // (12544,384) bf16
  char*  kv2   = ws + 14921984;               // 3072 x 18816 B  (end ~72.7 MB)

  prep_kernel<<<5, 256, 0, stream>>>(
      (const float*)d_in[2],  (const float*)d_in[3],  (const float*)d_in[4],  (const float*)d_in[5],
      (const float*)d_in[7],  (const float*)d_in[8],  (const float*)d_in[9],  (const float*)d_in[10],
      (const float*)d_in[12], (const float*)d_in[13], (const float*)d_in[14], (const float*)d_in[15],
      scbuf);
  bias_kernel<<<451, 256, 0, stream>>>(biases, bidx, biasp);
  // q = BN(xq @ q_w^T): M=12544, N=192 -> per-(b,h) q blocks
  gemm_bn_kernel<2, true, false><<<dim3(3, 98), 128, 0, stream>>>(
      x, q_w, scbuf + 1152, scbuf + 1344, qb2, 192);
  // kv = BN(x @ kv_w^T): M=50176, N=576 -> per-(b,h) k/vT blocks
  gemm_bn_kernel<1, false, false><<<dim3(9, 392), 128, 0, stream>>>(
      x, kv_w, scbuf, scbuf + 576, kv2, 576);
  // fused attention per (b,h)
  attn_kernel<<<3072, 256, 0, stream>>>(kv2, qb2, biasp, aout);
  // out = BN(silu_attn @ pj_w^T): M=12544, N=512, fp32 out
  gemm_bn_kernel<0, false, true><<<dim3(8, 98), 128, 0, stream>>>(
      aout, pj_w, scbuf + 1536, scbuf + 2048, (char*)d_out, 512);
}